// Round 11
// baseline (1004.107 us; speedup 1.0000x reference)
//
#include <hip/hip_runtime.h>
#include <math.h>

#define LEAKY(x) ((x) > 0.f ? (x) : 0.01f * (x))
static constexpr float BN_SCALE = 0.9999950000374997f;

typedef unsigned short ushort_t;
typedef float f32x4 __attribute__((ext_vector_type(4)));
typedef short bf16x8 __attribute__((ext_vector_type(8)));

__device__ __forceinline__ ushort_t f2bfu(float f) {
  union { float f; unsigned u; } v; v.f = f;
  unsigned r = v.u + 0x7fffu + ((v.u >> 16) & 1u);
  return (ushort_t)(r >> 16);
}
__device__ __forceinline__ float bfu2f(ushort_t u) {
  union { unsigned u; float f; } v; v.u = ((unsigned)u) << 16;
  return v.f;
}

__global__ void fill_out(float* out, int n) {
  int i = blockIdx.x * 256 + threadIdx.x;
  if (i < n) out[i] = 0.25f;
}

// ---- one-shot fp32 -> bf16 conversion of up to 20 tensors -----------------
struct CvtArgs {
  const float* src[20];
  ushort_t* dst[20];
  int len[20];
};
__global__ void to_bf16_multi(CvtArgs a) {
  for (int s = 0; s < 20; ++s) {
    const float* sp = a.src[s];
    ushort_t* dp = a.dst[s];
    int n = a.len[s];
    for (int i = blockIdx.x * 256 + threadIdx.x; i < n; i += gridDim.x * 256)
      dp[i] = f2bfu(sp[i]);
  }
}

// ---- pack 6 bias pairs [128|128] -> fp32 [6][256] -------------------------
struct BiasPk { const float* a[12]; float* out; };
__global__ void bias_pack(BiasPk p) {
  int b = blockIdx.x, t = threadIdx.x;
  p.out[b * 256 + t] = (t < 128) ? p.a[2 * b][t] : p.a[2 * b + 1][t - 128];
}

// ---- pad fuse_w [256,460] fp32 -> [256,512] bf16 --------------------------
__global__ void pad_fuse_bf16(const float* __restrict__ w, ushort_t* __restrict__ wp) {
  int idx = blockIdx.x * 256 + threadIdx.x;
  if (idx >= 256 * 512) return;
  int o = idx >> 9, k = idx & 511;
  wp[idx] = (k < 460) ? f2bfu(w[(size_t)o * 460 + k]) : (ushort_t)0;
}

// ============================================================================
// Fused conv1+pool+conv2+pool via MFMA implicit GEMM. 2 images/block.
// Covers both B (blocks 0..1023) and KB (1024..2047) in one dispatch.
// Phase-1 patch loads use float2 (18 LDS ops instead of 36).
// ============================================================================
__launch_bounds__(256)
__global__ void conv12_mfma(const float* __restrict__ imgB, const float* __restrict__ imgK,
                            const float* __restrict__ w1, const float* __restrict__ b1,
                            const ushort_t* __restrict__ w2b, const float* __restrict__ b2,
                            ushort_t* __restrict__ out800) {
  __shared__ __align__(16) char smem[39168];
  ushort_t* sh1u = (ushort_t*)smem;
  float* simg = (float*)(smem + 11520);
  float* sw1  = (float*)(smem + 11520 + 6272);
  ushort_t* As = (ushort_t*)(smem + 11520);
  ushort_t* Bs = (ushort_t*)(smem + 29952);
  float* Cf = (float*)smem;

  int tid = threadIdx.x;
  int bx = blockIdx.x;
  const float* imgb = (bx < 1024) ? imgB + (size_t)bx * 2 * 784
                                  : imgK + (size_t)(bx - 1024) * 2 * 784;

  for (int i = tid; i < 1568; i += 256) simg[i] = imgb[i];
  for (int i = tid; i < 500; i += 256) sw1[i] = w1[i];
  __syncthreads();
  for (int o = tid; o < 5760; o += 256) {
    int im = o / 2880, oi = o % 2880;
    int c = oi / 144, rem = oi % 144, py = rem / 12, px = rem % 12;
    int y0 = py * 2, x0 = px * 2;
    const float* sb = &simg[im * 784];
    float p[6][6];
    #pragma unroll
    for (int yy = 0; yy < 6; ++yy) {
      const float2* row = (const float2*)(sb + (y0 + yy) * 28 + x0);
      float2 q0 = row[0], q1 = row[1], q2 = row[2];
      p[yy][0] = q0.x; p[yy][1] = q0.y; p[yy][2] = q1.x;
      p[yy][3] = q1.y; p[yy][4] = q2.x; p[yy][5] = q2.y;
    }
    float bb = b1[c];
    float t0 = bb, t1 = bb, t2 = bb, t3 = bb;
    const float* wc = &sw1[c * 25];
    #pragma unroll
    for (int ky = 0; ky < 5; ++ky)
      #pragma unroll
      for (int kx = 0; kx < 5; ++kx) {
        float wv = wc[ky * 5 + kx];
        t0 += p[ky][kx] * wv;
        t1 += p[ky][kx + 1] * wv;
        t2 += p[ky + 1][kx] * wv;
        t3 += p[ky + 1][kx + 1] * wv;
      }
    t0 = LEAKY(t0); t1 = LEAKY(t1); t2 = LEAKY(t2); t3 = LEAKY(t3);
    sh1u[o] = f2bfu(fmaxf(fmaxf(t0, t1), fmaxf(t2, t3)));
  }

  int wave = tid >> 6, lane = tid & 63;
  int wm = (wave >> 1) * 64, wn = (wave & 1) * 32;
  int mrow = lane & 15, kq = lane >> 4;
  int kl = tid & 63, rbase = tid >> 6;

  f32x4 acc[4][2];
  #pragma unroll
  for (int i = 0; i < 4; ++i)
    #pragma unroll
    for (int j = 0; j < 2; ++j)
      #pragma unroll
      for (int r = 0; r < 4; ++r) acc[i][j][r] = 0.f;

  for (int k0 = 0; k0 < 512; k0 += 64) {
    __syncthreads();
    int k = k0 + kl;
    bool valid = k < 500;
    int ic = k / 25, tap = k - ic * 25;
    int ky = tap / 5, kx = tap - ky * 5;
    int kof = ic * 144 + ky * 12 + kx;
    ushort_t tA[32];
    #pragma unroll
    for (int i = 0; i < 32; ++i) {
      int r = rbase + 4 * i;
      int im = r >> 6, pos = r & 63, oy = pos >> 3, ox = pos & 7;
      tA[i] = valid ? sh1u[im * 2880 + kof + oy * 12 + ox] : (ushort_t)0;
    }
    ushort_t tB[16];
    #pragma unroll
    for (int i = 0; i < 16; ++i) {
      int oc = rbase + 4 * i;
      tB[i] = (valid && oc < 50) ? w2b[(size_t)oc * 500 + k] : (ushort_t)0;
    }
    #pragma unroll
    for (int i = 0; i < 32; ++i) As[(rbase + 4 * i) * 72 + kl] = tA[i];
    #pragma unroll
    for (int i = 0; i < 16; ++i) Bs[(rbase + 4 * i) * 72 + kl] = tB[i];
    __syncthreads();
    #pragma unroll
    for (int ks = 0; ks < 2; ++ks) {
      bf16x8 af[4], bf[2];
      #pragma unroll
      for (int mt = 0; mt < 4; ++mt)
        af[mt] = *(const bf16x8*)&As[(wm + mt * 16 + mrow) * 72 + ks * 32 + kq * 8];
      #pragma unroll
      for (int nt = 0; nt < 2; ++nt)
        bf[nt] = *(const bf16x8*)&Bs[(wn + nt * 16 + mrow) * 72 + ks * 32 + kq * 8];
      #pragma unroll
      for (int mt = 0; mt < 4; ++mt)
        #pragma unroll
        for (int nt = 0; nt < 2; ++nt)
          acc[mt][nt] = __builtin_amdgcn_mfma_f32_16x16x32_bf16(af[mt], bf[nt], acc[mt][nt], 0, 0, 0);
    }
  }
  __syncthreads();
  #pragma unroll
  for (int mt = 0; mt < 4; ++mt)
    #pragma unroll
    for (int nt = 0; nt < 2; ++nt) {
      int n0 = wn + nt * 16 + (lane & 15);
      #pragma unroll
      for (int r = 0; r < 4; ++r)
        Cf[(wm + mt * 16 + kq * 4 + r) * 68 + n0] = acc[mt][nt][r];
    }
  __syncthreads();
  for (int o = tid; o < 1600; o += 256) {
    int im = o / 800, oi = o - im * 800;
    int oc = oi >> 4, p = oi & 15, py = p >> 2, px = p & 3;
    int r0 = im * 64 + py * 16 + px * 2;
    float bb = b2[oc];
    float t0 = LEAKY(Cf[r0 * 68 + oc] + bb);
    float t1 = LEAKY(Cf[(r0 + 1) * 68 + oc] + bb);
    float t2 = LEAKY(Cf[(r0 + 8) * 68 + oc] + bb);
    float t3 = LEAKY(Cf[(r0 + 9) * 68 + oc] + bb);
    out800[(size_t)(bx * 2 + im) * 800 + oi] = f2bfu(fmaxf(fmaxf(t0, t1), fmaxf(t2, t3)));
  }
}

enum { EPI_NONE = 0, EPI_LEAKY = 1, EPI_LEAKY_BN = 2, EPI_TANH = 3, EPI_EUCLID = 4 };

#define LROW 40

// ---- 128x128 bf16 NT GEMM, BK=64 (K%64==0). euclid / skip3 X3b ------------
template <int EPI>
__launch_bounds__(256)
__global__ void gemm_bf16_nt(const ushort_t* __restrict__ A, const ushort_t* __restrict__ B,
                             const float* __restrict__ bias, float* __restrict__ C32,
                             ushort_t* __restrict__ C16, int M, int N, int Kd,
                             const float* __restrict__ e1, const float* __restrict__ e2) {
  __shared__ ushort_t As[128 * 72];
  __shared__ ushort_t Bs[128 * 72];
  int tid = threadIdx.x;
  int bm = blockIdx.y * 128, bn = blockIdx.x * 128;
  int wave = tid >> 6, lane = tid & 63;
  int wm = (wave >> 1) * 64, wn = (wave & 1) * 64;
  int mrow = lane & 15, kq = lane >> 4;
  int srow = tid >> 1, skof = (tid & 1) * 32;

  f32x4 acc[4][4];
  #pragma unroll
  for (int i = 0; i < 4; ++i)
    #pragma unroll
    for (int j = 0; j < 4; ++j)
      #pragma unroll
      for (int r = 0; r < 4; ++r) acc[i][j][r] = 0.f;

  for (int k0 = 0; k0 < Kd; k0 += 64) {
    const ushort_t* ap = A + (size_t)(bm + srow) * Kd + k0 + skof;
    const ushort_t* bp = B + (size_t)(bn + srow) * Kd + k0 + skof;
    uint4 a[4], b[4];
    #pragma unroll
    for (int i = 0; i < 4; ++i) a[i] = *(const uint4*)(ap + 8 * i);
    #pragma unroll
    for (int i = 0; i < 4; ++i) b[i] = *(const uint4*)(bp + 8 * i);
    __syncthreads();
    #pragma unroll
    for (int i = 0; i < 4; ++i) *(uint4*)&As[srow * 72 + skof + 8 * i] = a[i];
    #pragma unroll
    for (int i = 0; i < 4; ++i) *(uint4*)&Bs[srow * 72 + skof + 8 * i] = b[i];
    __syncthreads();
    #pragma unroll
    for (int ks = 0; ks < 2; ++ks) {
      bf16x8 af[4], bf[4];
      #pragma unroll
      for (int mt = 0; mt < 4; ++mt)
        af[mt] = *(const bf16x8*)&As[(wm + mt * 16 + mrow) * 72 + ks * 32 + kq * 8];
      #pragma unroll
      for (int nt = 0; nt < 4; ++nt)
        bf[nt] = *(const bf16x8*)&Bs[(wn + nt * 16 + mrow) * 72 + ks * 32 + kq * 8];
      #pragma unroll
      for (int mt = 0; mt < 4; ++mt)
        #pragma unroll
        for (int nt = 0; nt < 4; ++nt)
          acc[mt][nt] = __builtin_amdgcn_mfma_f32_16x16x32_bf16(af[mt], bf[nt], acc[mt][nt], 0, 0, 0);
    }
  }
  #pragma unroll
  for (int mt = 0; mt < 4; ++mt)
    #pragma unroll
    for (int nt = 0; nt < 4; ++nt) {
      int n_g = bn + wn + nt * 16 + (lane & 15);
      #pragma unroll
      for (int r = 0; r < 4; ++r) {
        int m_g = bm + wm + mt * 16 + kq * 4 + r;
        float v = acc[mt][nt][r];
        if (EPI == EPI_EUCLID) {
          v = e1[m_g] + e2[n_g] - 2.f * v;
          v = sqrtf(fmaxf(v, 0.f));
        } else {
          if (bias) v += bias[n_g];
          if (EPI == EPI_LEAKY) v = LEAKY(v);
          else if (EPI == EPI_LEAKY_BN) { v = LEAKY(v); v *= BN_SCALE; }
          else if (EPI == EPI_TANH) v = tanhf(v);
        }
        if (C32) C32[(size_t)m_g * N + n_g] = v;
        if (C16) C16[(size_t)m_g * N + n_g] = f2bfu(v);
      }
    }
}

// ---- Smat z-GEMM: Smat_z = X12_z[:, :128] @ X12_z[:, 128:]^T --------------
__launch_bounds__(256)
__global__ void gemm_smat_z(const ushort_t* __restrict__ X12, ushort_t* __restrict__ Smat) {
  int z = blockIdx.z;
  const ushort_t* A = X12 + (size_t)z * 2048 * 256;
  const ushort_t* B = A + 128;
  ushort_t* C = Smat + (size_t)z * 2048 * 2048;
  __shared__ ushort_t As[128 * LROW];
  __shared__ ushort_t Bs[128 * LROW];
  int tid = threadIdx.x;
  int bm = blockIdx.y * 128, bn = blockIdx.x * 128;
  int wave = tid >> 6, lane = tid & 63;
  int wm = (wave >> 1) * 64, wn = (wave & 1) * 64;
  int mrow = lane & 15, kq = lane >> 4;
  int srow = tid >> 1, skof = (tid & 1) * 16;

  f32x4 acc[4][4];
  #pragma unroll
  for (int i = 0; i < 4; ++i)
    #pragma unroll
    for (int j = 0; j < 4; ++j)
      #pragma unroll
      for (int r = 0; r < 4; ++r) acc[i][j][r] = 0.f;

  for (int k0 = 0; k0 < 128; k0 += 32) {
    const uint4* ap = (const uint4*)(A + (size_t)(bm + srow) * 256 + k0 + skof);
    const uint4* bp = (const uint4*)(B + (size_t)(bn + srow) * 256 + k0 + skof);
    uint4 a0 = ap[0], a1 = ap[1];
    uint4 b0 = bp[0], b1 = bp[1];
    __syncthreads();
    *(uint4*)&As[srow * LROW + skof] = a0;
    *(uint4*)&As[srow * LROW + skof + 8] = a1;
    *(uint4*)&Bs[srow * LROW + skof] = b0;
    *(uint4*)&Bs[srow * LROW + skof + 8] = b1;
    __syncthreads();
    bf16x8 af[4], bf[4];
    #pragma unroll
    for (int mt = 0; mt < 4; ++mt)
      af[mt] = *(const bf16x8*)&As[(wm + mt * 16 + mrow) * LROW + kq * 8];
    #pragma unroll
    for (int nt = 0; nt < 4; ++nt)
      bf[nt] = *(const bf16x8*)&Bs[(wn + nt * 16 + mrow) * LROW + kq * 8];
    #pragma unroll
    for (int mt = 0; mt < 4; ++mt)
      #pragma unroll
      for (int nt = 0; nt < 4; ++nt)
        acc[mt][nt] = __builtin_amdgcn_mfma_f32_16x16x32_bf16(af[mt], bf[nt], acc[mt][nt], 0, 0, 0);
  }
  #pragma unroll
  for (int mt = 0; mt < 4; ++mt)
    #pragma unroll
    for (int nt = 0; nt < 4; ++nt) {
      int n_g = bn + wn + nt * 16 + (lane & 15);
      #pragma unroll
      for (int r = 0; r < 4; ++r) {
        int m_g = bm + wm + mt * 16 + kq * 4 + r;
        C[(size_t)m_g * 2048 + n_g] = f2bfu(acc[mt][nt][r]);
      }
    }
}

// ---- 64x64 bf16 NT GEMM (BK=32, handles any K%32) -------------------------
template <int EPI>
__launch_bounds__(256)
__global__ void gemm_bf16_nt64(const ushort_t* __restrict__ A, const ushort_t* __restrict__ B,
                               const float* __restrict__ bias, float* __restrict__ C32,
                               ushort_t* __restrict__ C16, int M, int N, int Kd) {
  __shared__ ushort_t As[64 * LROW];
  __shared__ ushort_t Bs[64 * LROW];
  int tid = threadIdx.x;
  int bm = blockIdx.y * 64, bn = blockIdx.x * 64;
  int wave = tid >> 6, lane = tid & 63;
  int wm = (wave >> 1) * 32, wn = (wave & 1) * 32;
  int mrow = lane & 15, kq = lane >> 4;
  int srow = tid >> 2, skof = (tid & 3) * 8;

  f32x4 acc[2][2];
  #pragma unroll
  for (int i = 0; i < 2; ++i)
    #pragma unroll
    for (int j = 0; j < 2; ++j)
      #pragma unroll
      for (int r = 0; r < 4; ++r) acc[i][j][r] = 0.f;

  for (int k0 = 0; k0 < Kd; k0 += 32) {
    uint4 a0 = *(const uint4*)(A + (size_t)(bm + srow) * Kd + k0 + skof);
    uint4 b0 = *(const uint4*)(B + (size_t)(bn + srow) * Kd + k0 + skof);
    __syncthreads();
    *(uint4*)&As[srow * LROW + skof] = a0;
    *(uint4*)&Bs[srow * LROW + skof] = b0;
    __syncthreads();
    bf16x8 af[2], bf[2];
    #pragma unroll
    for (int mt = 0; mt < 2; ++mt)
      af[mt] = *(const bf16x8*)&As[(wm + mt * 16 + mrow) * LROW + kq * 8];
    #pragma unroll
    for (int nt = 0; nt < 2; ++nt)
      bf[nt] = *(const bf16x8*)&Bs[(wn + nt * 16 + mrow) * LROW + kq * 8];
    #pragma unroll
    for (int mt = 0; mt < 2; ++mt)
      #pragma unroll
      for (int nt = 0; nt < 2; ++nt)
        acc[mt][nt] = __builtin_amdgcn_mfma_f32_16x16x32_bf16(af[mt], bf[nt], acc[mt][nt], 0, 0, 0);
  }
  #pragma unroll
  for (int mt = 0; mt < 2; ++mt)
    #pragma unroll
    for (int nt = 0; nt < 2; ++nt) {
      int n_g = bn + wn + nt * 16 + (lane & 15);
      #pragma unroll
      for (int r = 0; r < 4; ++r) {
        int m_g = bm + wm + mt * 16 + kq * 4 + r;
        float v = acc[mt][nt][r];
        if (bias) v += bias[n_g];
        if (EPI == EPI_LEAKY) v = LEAKY(v);
        else if (EPI == EPI_LEAKY_BN) { v = LEAKY(v); v *= BN_SCALE; }
        else if (EPI == EPI_TANH) v = tanhf(v);
        if (C32) C32[(size_t)m_g * N + n_g] = v;
        if (C16) C16[(size_t)m_g * N + n_g] = f2bfu(v);
      }
    }
}

// ---- 64x64 NT GEMM, dual weight/bias selected by M-half -------------------
template <int EPI>
__launch_bounds__(256)
__global__ void gemm_nt64_dual(const ushort_t* __restrict__ A, const ushort_t* __restrict__ B1,
                               const ushort_t* __restrict__ B2, const float* __restrict__ bias1,
                               const float* __restrict__ bias2, ushort_t* __restrict__ C16,
                               int M, int N, int Kd, int Msplit) {
  __shared__ ushort_t As[64 * LROW];
  __shared__ ushort_t Bs[64 * LROW];
  int tid = threadIdx.x;
  int bm = blockIdx.y * 64, bn = blockIdx.x * 64;
  const ushort_t* B = (bm < Msplit) ? B1 : B2;
  const float* bias = (bm < Msplit) ? bias1 : bias2;
  int wave = tid >> 6, lane = tid & 63;
  int wm = (wave >> 1) * 32, wn = (wave & 1) * 32;
  int mrow = lane & 15, kq = lane >> 4;
  int srow = tid >> 2, skof = (tid & 3) * 8;

  f32x4 acc[2][2];
  #pragma unroll
  for (int i = 0; i < 2; ++i)
    #pragma unroll
    for (int j = 0; j < 2; ++j)
      #pragma unroll
      for (int r = 0; r < 4; ++r) acc[i][j][r] = 0.f;

  for (int k0 = 0; k0 < Kd; k0 += 32) {
    uint4 a0 = *(const uint4*)(A + (size_t)(bm + srow) * Kd + k0 + skof);
    uint4 b0 = *(const uint4*)(B + (size_t)(bn + srow) * Kd + k0 + skof);
    __syncthreads();
    *(uint4*)&As[srow * LROW + skof] = a0;
    *(uint4*)&Bs[srow * LROW + skof] = b0;
    __syncthreads();
    bf16x8 af[2], bf[2];
    #pragma unroll
    for (int mt = 0; mt < 2; ++mt)
      af[mt] = *(const bf16x8*)&As[(wm + mt * 16 + mrow) * LROW + kq * 8];
    #pragma unroll
    for (int nt = 0; nt < 2; ++nt)
      bf[nt] = *(const bf16x8*)&Bs[(wn + nt * 16 + mrow) * LROW + kq * 8];
    #pragma unroll
    for (int mt = 0; mt < 2; ++mt)
      #pragma unroll
      for (int nt = 0; nt < 2; ++nt)
        acc[mt][nt] = __builtin_amdgcn_mfma_f32_16x16x32_bf16(af[mt], bf[nt], acc[mt][nt], 0, 0, 0);
  }
  #pragma unroll
  for (int mt = 0; mt < 2; ++mt)
    #pragma unroll
    for (int nt = 0; nt < 2; ++nt) {
      int n_g = bn + wn + nt * 16 + (lane & 15);
      #pragma unroll
      for (int r = 0; r < 4; ++r) {
        int m_g = bm + wm + mt * 16 + kq * 4 + r;
        float v = acc[mt][nt][r] + bias[n_g];
        if (EPI == EPI_LEAKY) v = LEAKY(v);
        else if (EPI == EPI_LEAKY_BN) { v = LEAKY(v); v *= BN_SCALE; }
        C16[(size_t)m_g * N + n_g] = f2bfu(v);
      }
    }
}

// ---- 64x64 NT GEMM with column-split epilogue (EPI1 for n<Nsplit) ---------
template <int EPI1, int EPI2>
__launch_bounds__(256)
__global__ void gemm_nt64_split(const ushort_t* __restrict__ A, const ushort_t* __restrict__ B,
                                const float* __restrict__ biasPk, float* __restrict__ C32,
                                ushort_t* __restrict__ C16, int M, int N, int Kd, int Nsplit) {
  __shared__ ushort_t As[64 * LROW];
  __shared__ ushort_t Bs[64 * LROW];
  int tid = threadIdx.x;
  int bm = blockIdx.y * 64, bn = blockIdx.x * 64;
  int wave = tid >> 6, lane = tid & 63;
  int wm = (wave >> 1) * 32, wn = (wave & 1) * 32;
  int mrow = lane & 15, kq = lane >> 4;
  int srow = tid >> 2, skof = (tid & 3) * 8;

  f32x4 acc[2][2];
  #pragma unroll
  for (int i = 0; i < 2; ++i)
    #pragma unroll
    for (int j = 0; j < 2; ++j)
      #pragma unroll
      for (int r = 0; r < 4; ++r) acc[i][j][r] = 0.f;

  for (int k0 = 0; k0 < Kd; k0 += 32) {
    uint4 a0 = *(const uint4*)(A + (size_t)(bm + srow) * Kd + k0 + skof);
    uint4 b0 = *(const uint4*)(B + (size_t)(bn + srow) * Kd + k0 + skof);
    __syncthreads();
    *(uint4*)&As[srow * LROW + skof] = a0;
    *(uint4*)&Bs[srow * LROW + skof] = b0;
    __syncthreads();
    bf16x8 af[2], bf[2];
    #pragma unroll
    for (int mt = 0; mt < 2; ++mt)
      af[mt] = *(const bf16x8*)&As[(wm + mt * 16 + mrow) * LROW + kq * 8];
    #pragma unroll
    for (int nt = 0; nt < 2; ++nt)
      bf[nt] = *(const bf16x8*)&Bs[(wn + nt * 16 + mrow) * LROW + kq * 8];
    #pragma unroll
    for (int mt = 0; mt < 2; ++mt)
      #pragma unroll
      for (int nt = 0; nt < 2; ++nt)
        acc[mt][nt] = __builtin_amdgcn_mfma_f32_16x16x32_bf16(af[mt], bf[nt], acc[mt][nt], 0, 0, 0);
  }
  #pragma unroll
  for (int mt = 0; mt < 2; ++mt)
    #pragma unroll
    for (int nt = 0; nt < 2; ++nt) {
      int n_g = bn + wn + nt * 16 + (lane & 15);
      #pragma unroll
      for (int r = 0; r < 4; ++r) {
        int m_g = bm + wm + mt * 16 + kq * 4 + r;
        float v = acc[mt][nt][r] + biasPk[n_g];
        if (n_g < Nsplit) {
          if (EPI1 == EPI_LEAKY) v = LEAKY(v);
          else if (EPI1 == EPI_TANH) v = tanhf(v);
        } else {
          if (EPI2 == EPI_LEAKY) v = LEAKY(v);
          else if (EPI2 == EPI_TANH) v = tanhf(v);
        }
        if (C32) C32[(size_t)m_g * N + n_g] = v;
        if (C16) C16[(size_t)m_g * N + n_g] = f2bfu(v);
      }
    }
}

// ---- 128x128 bf16 NN GEMM + bf16 residual, BK=64 (skip3) ------------------
__launch_bounds__(256)
__global__ void gemm_bf16_nn_res(const ushort_t* __restrict__ A, const ushort_t* __restrict__ B,
                                 const ushort_t* __restrict__ R, ushort_t* __restrict__ C16,
                                 int M, int N, int Kd) {
  __shared__ ushort_t As[128 * 72];
  __shared__ ushort_t Bs[128 * 72];
  int tid = threadIdx.x;
  int bm = blockIdx.y * 128, bn = blockIdx.x * 128;
  int wave = tid >> 6, lane = tid & 63;
  int wm = (wave >> 1) * 64, wn = (wave & 1) * 64;
  int mrow = lane & 15, kq = lane >> 4;
  int srow = tid >> 1, skof = (tid & 1) * 32;
  int krow = tid >> 2, nof = (tid & 3) * 32;

  f32x4 acc[4][4];
  #pragma unroll
  for (int i = 0; i < 4; ++i)
    #pragma unroll
    for (int j = 0; j < 4; ++j)
      #pragma unroll
      for (int r = 0; r < 4; ++r) acc[i][j][r] = 0.f;

  for (int k0 = 0; k0 < Kd; k0 += 64) {
    const ushort_t* ap = A + (size_t)(bm + srow) * Kd + k0 + skof;
    uint4 a[4];
    #pragma unroll
    for (int i = 0; i < 4; ++i) a[i] = *(const uint4*)(ap + 8 * i);
    ushort_t bb[32];
    const ushort_t* bp = B + (size_t)(k0 + krow) * N + bn + nof;
    #pragma unroll
    for (int i = 0; i < 4; ++i) *(uint4*)&bb[8 * i] = *(const uint4*)(bp + 8 * i);
    __syncthreads();
    #pragma unroll
    for (int i = 0; i < 4; ++i) *(uint4*)&As[srow * 72 + skof + 8 * i] = a[i];
    #pragma unroll
    for (int j = 0; j < 32; ++j)
      Bs[(nof + j) * 72 + krow] = bb[j];
    __syncthreads();
    #pragma unroll
    for (int ks = 0; ks < 2; ++ks) {
      bf16x8 af[4], bf[4];
      #pragma unroll
      for (int mt = 0; mt < 4; ++mt)
        af[mt] = *(const bf16x8*)&As[(wm + mt * 16 + mrow) * 72 + ks * 32 + kq * 8];
      #pragma unroll
      for (int nt = 0; nt < 4; ++nt)
        bf[nt] = *(const bf16x8*)&Bs[(wn + nt * 16 + mrow) * 72 + ks * 32 + kq * 8];
      #pragma unroll
      for (int mt = 0; mt < 4; ++mt)
        #pragma unroll
        for (int nt = 0; nt < 4; ++nt)
          acc[mt][nt] = __builtin_amdgcn_mfma_f32_16x16x32_bf16(af[mt], bf[nt], acc[mt][nt], 0, 0, 0);
    }
  }
  #pragma unroll
  for (int mt = 0; mt < 4; ++mt)
    #pragma unroll
    for (int nt = 0; nt < 4; ++nt) {
      int n_g = bn + wn + nt * 16 + (lane & 15);
      #pragma unroll
      for (int r = 0; r < 4; ++r) {
        int m_g = bm + wm + mt * 16 + kq * 4 + r;
        float v = acc[mt][nt][r] + bfu2f(R[(size_t)m_g * N + n_g]);
        C16[(size_t)m_g * N + n_g] = f2bfu(v);
      }
    }
}

// ---- 64x64 NN GEMM + residual, BK=64, z over both skip branches -----------
__launch_bounds__(256)
__global__ void gemm_nn_res64_z(const ushort_t* __restrict__ SmatBase,
                                const ushort_t* __restrict__ X3sb,
                                const ushort_t* __restrict__ dtb,
                                ushort_t* __restrict__ XsKs) {
  int z = blockIdx.z;
  const ushort_t* A = SmatBase + (size_t)z * 2048 * 2048;
  const ushort_t* B = X3sb + (size_t)z * 2048 * 256;
  const ushort_t* R = dtb + (size_t)z * 2048 * 256;
  ushort_t* C = XsKs + (size_t)z * 2048 * 256;
  const int N = 256, Kd = 2048;
  __shared__ ushort_t As[64 * 72];
  __shared__ ushort_t Bs[64 * 72];
  int tid = threadIdx.x;
  int bm = blockIdx.y * 64, bn = blockIdx.x * 64;
  int wave = tid >> 6, lane = tid & 63;
  int wm = (wave >> 1) * 32, wn = (wave & 1) * 32;
  int mrow = lane & 15, kq = lane >> 4;
  int srow = tid >> 2, skof = (tid & 3) * 16;
  int krow = tid >> 2, nof = (tid & 3) * 16;

  f32x4 acc[2][2];
  #pragma unroll
  for (int i = 0; i < 2; ++i)
    #pragma unroll
    for (int j = 0; j < 2; ++j)
      #pragma unroll
      for (int r = 0; r < 4; ++r) acc[i][j][r] = 0.f;

  for (int k0 = 0; k0 < Kd; k0 += 64) {
    const ushort_t* ap = A + (size_t)(bm + srow) * Kd + k0 + skof;
    uint4 a0 = *(const uint4*)(ap);
    uint4 a1 = *(const uint4*)(ap + 8);
    ushort_t bb[16];
    const ushort_t* bp = B + (size_t)(k0 + krow) * N + bn + nof;
    *(uint4*)&bb[0] = *(const uint4*)(bp);
    *(uint4*)&bb[8] = *(const uint4*)(bp + 8);
    __syncthreads();
    *(uint4*)&As[srow * 72 + skof] = a0;
    *(uint4*)&As[srow * 72 + skof + 8] = a1;
    #pragma unroll
    for (int j = 0; j < 16; ++j)
      Bs[(nof + j) * 72 + krow] = bb[j];
    __syncthreads();
    #pragma unroll
    for (int ks = 0; ks < 2; ++ks) {
      bf16x8 af[2], bf[2];
      #pragma unroll
      for (int mt = 0; mt < 2; ++mt)
        af[mt] = *(const bf16x8*)&As[(wm + mt * 16 + mrow) * 72 + ks * 32 + kq * 8];
      #pragma unroll
      for (int nt = 0; nt < 2; ++nt)
        bf[nt] = *(const bf16x8*)&Bs[(wn + nt * 16 + mrow) * 72 + ks * 32 + kq * 8];
      #pragma unroll
      for (int mt = 0; mt < 2; ++mt)
        #pragma unroll
        for (int nt = 0; nt < 2; ++nt)
          acc[mt][nt] = __builtin_amdgcn_mfma_f32_16x16x32_bf16(af[mt], bf[nt], acc[mt][nt], 0, 0, 0);
    }
  }
  #pragma unroll
  for (int mt = 0; mt < 2; ++mt)
    #pragma unroll
    for (int nt = 0; nt < 2; ++nt) {
      int n_g = bn + wn + nt * 16 + (lane & 15);
      #pragma unroll
      for (int r = 0; r < 4; ++r) {
        int m_g = bm + wm + mt * 16 + kq * 4 + r;
        float v = acc[mt][nt][r] + bfu2f(R[(size_t)m_g * N + n_g]);
        C[(size_t)m_g * N + n_g] = f2bfu(v);
      }
    }
}

// ---- split-K TN GEMM: Mm = X12m[:, :128]^T @ X12m[:, 128:] ----------------
__global__ void gemm_tn_part(const ushort_t* __restrict__ X, float* __restrict__ part) {
  int tx = threadIdx.x & 15, ty = threadIdx.x >> 4;
  int i = blockIdx.y * 16 + ty, j = blockIdx.x * 16 + tx;
  int ks = blockIdx.z;
  float acc = 0.f;
  for (int k = ks * 128; k < ks * 128 + 128; ++k)
    acc += bfu2f(X[(size_t)k * 256 + i]) * bfu2f(X[(size_t)k * 256 + 128 + j]);
  part[(size_t)ks * 16384 + i * 128 + j] = acc;
}
__global__ void gemm_tn_reduce(const float* __restrict__ part, ushort_t* __restrict__ Mm) {
  int idx = blockIdx.x * 256 + threadIdx.x;
  float s = 0.f;
  #pragma unroll
  for (int ks = 0; ks < 16; ++ks) s += part[(size_t)ks * 16384 + idx];
  Mm[idx] = f2bfu(s);
}

// ---- 3-stage column softmax with z over matrices --------------------------
__global__ void smax_partA(const ushort_t* __restrict__ Sb, float* __restrict__ pm,
                           float* __restrict__ pl, int N) {
  int z = blockIdx.z;
  const ushort_t* S = Sb + (size_t)z * 2048 * 2048;
  int t = threadIdx.x;
  int col = blockIdx.x * 64 + (t & 63);
  int g = t >> 6;
  int r0 = blockIdx.y * 128 + g;
  float vals[32];
  #pragma unroll
  for (int i = 0; i < 32; ++i)
    vals[i] = bfu2f(S[(size_t)(r0 + 4 * i) * N + col]);
  float m = -1e30f;
  #pragma unroll
  for (int i = 0; i < 32; ++i) m = fmaxf(m, vals[i]);
  float l = 0.f;
  #pragma unroll
  for (int i = 0; i < 32; ++i) l += expf(vals[i] - m);
  __shared__ float rm[4][64], rl[4][64];
  rm[g][t & 63] = m; rl[g][t & 63] = l;
  __syncthreads();
  if (g == 0) {
    int c = t & 63;
    float M0 = rm[0][c], L0 = rl[0][c];
    #pragma unroll
    for (int j = 1; j < 4; ++j) {
      float Mj = rm[j][c], Lj = rl[j][c];
      float nm = fmaxf(M0, Mj);
      L0 = L0 * expf(M0 - nm) + Lj * expf(Mj - nm);
      M0 = nm;
    }
    pm[((size_t)z * 16 + blockIdx.y) * N + col] = M0;
    pl[((size_t)z * 16 + blockIdx.y) * N + col] = L0;
  }
}
__global__ void smax_partB(const float* __restrict__ pm, const float* __restrict__ pl,
                           float* __restrict__ gm, float* __restrict__ gi, int N) {
  int z = blockIdx.y;
  int col = blockIdx.x * 256 + threadIdx.x;
  float m = -1e30f, l = 0.f;
  for (int b = 0; b < 16; ++b) {
    float bm = pm[((size_t)z * 16 + b) * N + col], bl = pl[((size_t)z * 16 + b) * N + col];
    float nm = fmaxf(m, bm);
    l = l * expf(m - nm) + bl * expf(bm - nm);
    m = nm;
  }
  gm[(size_t)z * N + col] = m;
  gi[(size_t)z * N + col] = 1.f / l;
}
__global__ void smax_partC(ushort_t* __restrict__ Sb, const float* __restrict__ gm,
                           const float* __restrict__ gi, int N) {
  int z = blockIdx.z;
  ushort_t* S = Sb + (size_t)z * 2048 * 2048;
  int t = threadIdx.x;
  int col = blockIdx.x * 64 + (t & 63);
  int g = t >> 6;
  float m = gm[(size_t)z * N + col], inv = gi[(size_t)z * N + col];
  int r0 = blockIdx.y * 128 + g;
  #pragma unroll 8
  for (int i = 0; i < 32; ++i) {
    size_t idx = (size_t)(r0 + 4 * i) * N + col;
    S[idx] = f2bfu(expf(bfu2f(S[idx]) - m) * inv);
  }
}

// ---- row squared-norms from bf16 ------------------------------------------
__global__ void row_norm_bf16(const ushort_t* __restrict__ X, float* __restrict__ out, int Kd) {
  int r = blockIdx.x;
  int t = threadIdx.x;
  float s = 0.f;
  for (int k = t; k < Kd; k += 64) { float v = bfu2f(X[(size_t)r * Kd + k]); s += v * v; }
  for (int off = 32; off; off >>= 1) s += __shfl_down(s, off);
  if (t == 0) out[r] = s;
}

// ---- mask scores ----------------------------------------------------------
__global__ void mask_score(const float* __restrict__ A3, const float* __restrict__ w4,
                           const float* __restrict__ b4, float* __restrict__ s) {
  int k = blockIdx.x * 256 + threadIdx.x;
  float acc = b4[0];
  for (int h = 0; h < 128; ++h) acc += A3[(size_t)h * 2048 + k] * w4[h];
  s[k] = acc;
}

// ---- stable descending-argsort rank via LDS-staged scores -----------------
__global__ void topk_rank(const float* __restrict__ s, int* __restrict__ idx, int K, int S) {
  __shared__ float sv[2048];
  int t = threadIdx.x;
  for (int i = t; i < K; i += 256) sv[i] = s[i];
  __syncthreads();
  int j = blockIdx.x * 256 + t;
  if (j >= K) return;
  float sj = sv[j];
  int rank = 0;
  #pragma unroll 8
  for (int i = 0; i < 2048; ++i) {
    float si = sv[i];
    rank += (si > sj) || (si == sj && i < j);
  }
  if (rank < S) idx[rank] = j;
}

// ---- build cat = [B_dt | softmax(aff_s[:,idx],axis=1) | 0pad], bf16 -------
__global__ void build_cat(const ushort_t* __restrict__ Bdt, const ushort_t* __restrict__ affs,
                          const int* __restrict__ idx, ushort_t* __restrict__ cat) {
  int r = blockIdx.x, t = threadIdx.x;
  __shared__ float vals[256];
  __shared__ float red[256];
  float v = -1e30f;
  if (t < 204) {
    int ix = idx[t];
    ix = ix < 0 ? 0 : (ix > 2047 ? 2047 : ix);
    v = bfu2f(affs[(size_t)r * 2048 + ix]);
  }
  vals[t] = v;
  red[t] = v;
  __syncthreads();
  for (int off = 128; off; off >>= 1) { if (t < off) red[t] = fmaxf(red[t], red[t + off]); __syncthreads(); }
  float m = red[0];
  __syncthreads();
  float e = (t < 204) ? expf(vals[t] - m) : 0.f;
  red[t] = e;
  __syncthreads();
  for (int off = 128; off; off >>= 1) { if (t < off) red[t] += red[t + off]; __syncthreads(); }
  float inv = 1.f / red[0];
  cat[(size_t)r * 512 + t] = Bdt[(size_t)r * 256 + t];
  cat[(size_t)r * 512 + 256 + t] = (t < 204) ? f2bfu(e * inv) : (ushort_t)0;
}

// ---- a = leaky((AV*AU) @ aww.T + awb), AVU combined [2048,256] ------------
__global__ void attn_gate(const float* __restrict__ AVU, const float* __restrict__ aww,
                          const float* __restrict__ awb, float* __restrict__ a, int n) {
  int wave = threadIdx.x >> 6, lane = threadIdx.x & 63;
  int r = blockIdx.x * 4 + wave;
  if (r >= n) return;
  float s = 0.f;
  #pragma unroll
  for (int j = 0; j < 2; ++j) {
    int d = lane + 64 * j;
    s += AVU[(size_t)r * 256 + d] * AVU[(size_t)r * 256 + 128 + d] * aww[d];
  }
  for (int off = 32; off; off >>= 1) s += __shfl_down(s, off);
  if (lane == 0) {
    float acc = s + awb[0];
    a[r] = LEAKY(acc);
  }
}

// ---- 1-D softmax (single block) -------------------------------------------
__global__ void softmax_vec(const float* __restrict__ x, float* __restrict__ y,
                            float* __restrict__ y2, int n) {
  __shared__ float red[256];
  int t = threadIdx.x;
  float m = -1e30f;
  for (int i = t; i < n; i += 256) m = fmaxf(m, x[i]);
  red[t] = m;
  __syncthreads();
  for (int off = 128; off; off >>= 1) { if (t < off) red[t] = fmaxf(red[t], red[t + off]); __syncthreads(); }
  m = red[0];
  __syncthreads();
  float s = 0.f;
  for (int i = t; i < n; i += 256) s += expf(x[i] - m);
  red[t] = s;
  __syncthreads();
  for (int off = 128; off; off >>= 1) { if (t < off) red[t] += red[t + off]; __syncthreads(); }
  float inv = 1.f / red[0];
  for (int i = t; i < n; i += 256) {
    float v = expf(x[i] - m) * inv;
    y[i] = v;
    if (y2) y2[i] = v;
  }
}

// ---- weighted column sum over bf16 H, two-stage ---------------------------
__global__ void colsum_part(const float* __restrict__ wv, const ushort_t* __restrict__ H,
                            float* __restrict__ part, int n) {
  int bk = blockIdx.x, c = threadIdx.x;
  float s = 0.f;
  for (int r = bk; r < n; r += 16) s += wv[r] * bfu2f(H[(size_t)r * 256 + c]);
  part[bk * 256 + c] = s;
}
__global__ void colsum_fin(const float* __restrict__ part, float* __restrict__ out) {
  int c = threadIdx.x;
  float s = 0.f;
  #pragma unroll
  for (int k = 0; k < 16; ++k) s += part[k * 256 + c];
  out[c] = s;
}

// ---- small gemv -----------------------------------------------------------
__global__ void gemv_act(const float* __restrict__ x, const float* __restrict__ W,
                         const float* __restrict__ b, float* __restrict__ out,
                         int O, int Kd, int act) {
  int o = blockIdx.x * blockDim.x + threadIdx.x;
  if (o >= O) return;
  float acc = b ? b[o] : 0.f;
  for (int k = 0; k < Kd; ++k) acc += x[k] * W[(size_t)o * Kd + k];
  if (act == 1) acc = LEAKY(acc);
  out[o] = acc;
}

// ---- cat2 = [B_fuse | tile(M1)], bf16 -------------------------------------
__global__ void build_cat2(const ushort_t* __restrict__ Bf, const float* __restrict__ M1,
                           ushort_t* __restrict__ cat2) {
  int r = blockIdx.x, t = threadIdx.x;
  cat2[(size_t)r * 512 + t] = (t < 256) ? Bf[(size_t)r * 256 + t] : f2bfu(M1[t - 256]);
}

// ---- final head -----------------------------------------------------------
__global__ void final_head(const float* __restrict__ AH2, const float* __restrict__ embw,
                           const float* __restrict__ embb, const float* __restrict__ sembw,
                           const float* __restrict__ sembb, const float* __restrict__ clsw,
                           const float* __restrict__ clsb, float* __restrict__ Yout) {
  __shared__ float bvec[512];
  __shared__ float red[512];
  int t = threadIdx.x;
  float acc = embb[t];
  for (int c = 0; c < 256; ++c) acc += AH2[c] * embw[(size_t)t * 256 + c];
  bvec[t] = LEAKY(acc);
  __syncthreads();
  float p = 0.f;
  if (t < 256) {
    float a2 = sembb[t];
    for (int c = 0; c < 512; ++c) a2 += bvec[c] * sembw[(size_t)t * 512 + c];
    a2 = LEAKY(a2);
    p = a2 * clsw[t];
  }
  red[t] = p;
  __syncthreads();
  for (int off = 256; off; off >>= 1) { if (t < off) red[t] += red[t + off]; __syncthreads(); }
  if (t == 0) {
    float y = red[0] + clsb[0];
    y = 1.f / (1.f + expf(-y));
    y = fminf(fmaxf(y, 1e-5f), 1.f - 1e-5f);
    Yout[0] = y;
  }
}

extern "C" void kernel_launch(void* const* d_in, const int* in_sizes, int n_in,
                              void* d_out, int out_size, void* d_ws, size_t ws_size,
                              hipStream_t stream) {
  auto IN = [&](int i) { return (const float*)d_in[i]; };
  (void)n_in; (void)in_sizes; (void)out_size;

  const int S = 204;
  float* out_f = (float*)d_out;

  float* W = (float*)d_ws;
  size_t off = 0;
  auto F = [&](size_t n) { float* p = W + off; off += n; return p; };
  auto FU = [&](size_t nus) { return (ushort_t*)F((nus + 1) / 2); };

  ushort_t* dt_b  = FU((size_t)4096 * 256);
  ushort_t* XsKs  = FU((size_t)4096 * 256);
  ushort_t* X12b  = FU((size_t)4096 * 256);
  ushort_t* X3sb  = FU((size_t)4096 * 256);
  ushort_t* aff_b = FU((size_t)2048 * 2048);
  float* AVU   = F((size_t)2048 * 256);
  ushort_t* Mm_b = FU((size_t)128 * 128);
  float* svec  = F(2048);
  int*   idxb  = (int*)F(256);
  float* avec  = F(2048);
  float* Awv   = F(2048);
  float* AH    = F(256);
  float* M1v   = F(256);
  float* AH2   = F(256);
  float* nxy   = F(4096);
  float* part  = F(4096);
  float* sm_pm = F((size_t)2 * 16 * 2048);
  float* sm_pl = F((size_t)2 * 16 * 2048);
  float* sm_gm = F(2 * 2048);
  float* sm_gi = F(2 * 2048);
  float* pbias = F(6 * 256);

  size_t wo = 0;
  ushort_t* warena = (ushort_t*)F(3227872);
  auto WA = [&](size_t n) { ushort_t* p = warena + wo; wo = (wo + n + 15) & ~(size_t)15; return p; };
  ushort_t* w2b   = WA(25000);
  ushort_t* embb_ = WA(204800);
  ushort_t* s1w1 = WA(32768); ushort_t* s1w2 = WA(32768); ushort_t* s1w3 = WA(65536);
  ushort_t* s2w1 = WA(32768); ushort_t* s2w2 = WA(32768); ushort_t* s2w3 = WA(65536);
  ushort_t* s3w1 = WA(262144); ushort_t* s3w2 = WA(262144); ushort_t* s3w3 = WA(4194304);
  ushort_t* mw1 = WA(262144); ushort_t* mw2 = WA(262144); ushort_t* mw3 = WA(262144);
  ushort_t* fwp = WA(131072);
  ushort_t* a1fe = WA(65536); ushort_t* a1v = WA(32768); ushort_t* a1u = WA(32768);
  ushort_t* a2fe = WA(131072); ushort_t* a2v = WA(32768); ushort_t* a2u = WA(32768);
  (void)s1w2; (void)s2w2; (void)s3w2; (void)mw2; (void)a1u; (void)a2u;

  float* pool = F((size_t)4194304);

  const size_t NEED_BYTES = off * 4;
  if (ws_size < NEED_BYTES) {
    fill_out<<<9, 256, 0, stream>>>(out_f, 2049);
    return;
  }

  ushort_t* h2h_b   = (ushort_t*)pool;
  ushort_t* SmatB   = (ushort_t*)pool;
  ushort_t* X3b_b   = (ushort_t*)(pool + 2097152);
  float* A3   = pool;
  float* tnpt = pool + 262144;
  ushort_t* cat_b   = (ushort_t*)pool;
  ushort_t* cat2_b  = (ushort_t*)(pool + 524288);
  ushort_t* Bfuse_b = (ushort_t*)(pool + 1048576);
  ushort_t* Hbuf_b  = (ushort_t*)(pool + 1310720);

  // ---- weight conversion + packing ----
  CvtArgs ca;
  const float* srcs[20] = { IN(4), IN(6), IN(8), IN(10), IN(12), IN(14), IN(16), IN(18),
                            IN(20), IN(22), IN(24), IN(26), IN(28), IN(30),
                            IN(36), IN(38), IN(40), IN(46), IN(48), IN(50) };
  ushort_t* dsts[20] = { w2b, embb_, s1w1, s1w2, s1w3, s2w1, s2w2, s2w3,
                         s3w1, s3w2, s3w3, mw1, mw2, mw3,
                         a1fe, a1v, a1u, a2fe, a2v, a2u };
  int lens[20] = { 25000, 204800, 32768, 32768, 65536, 32768, 32768, 65536,
                   262144, 262144, 4194304, 262144, 262144, 262144,
                   65536, 32768, 32768, 131072, 32768, 32768 };
  for (int i = 0; i < 20; ++i) { ca.src[i] = srcs[i]; ca.dst[i] = dsts[i]; ca.len[i] = lens[i]; }
  to_bf16_multi<<<1024, 256, 0, stream>>>(ca);
  pad_fuse_bf16<<<512, 256, 0, stream>>>(IN(34), fwp);
  BiasPk bp;
  const float* bsrc[12] = { IN(9), IN(11), IN(15), IN(17), IN(21), IN(23),
                            IN(27), IN(29), IN(39), IN(41), IN(49), IN(51) };
  for (int i = 0; i < 12; ++i) bp.a[i] = bsrc[i];
  bp.out = pbias;
  bias_pack<<<6, 256, 0, stream>>>(bp);
  float* pb_sk1 = pbias, *pb_sk2 = pbias + 256, *pb_sk3 = pbias + 512;
  float* pb_msk = pbias + 768, *pb_a1 = pbias + 1024, *pb_a2 = pbias + 1280;

  // ---- conv + embedding ----
  conv12_mfma<<<2048, 256, 0, stream>>>(IN(0), IN(1), IN(2), IN(3), w2b, IN(5), h2h_b);
  gemm_bf16_nt64<EPI_LEAKY><<<dim3(4, 64), 256, 0, stream>>>(
      h2h_b, embb_, IN(7), nullptr, dt_b, 4096, 256, 800);

  // ---- skip1+skip2, both branches fused ----
  gemm_nt64_dual<EPI_LEAKY_BN><<<dim3(4, 64), 256, 0, stream>>>(
      dt_b, s1w1, s2w1, pb_sk1, pb_sk2, X12b, 4096, 256, 256, 2048);
  gemm_nt64_dual<EPI_LEAKY_BN><<<dim3(4, 64), 256, 0, stream>>>(
      dt_b, s1w3, s2w3, IN(13), IN(19), X3sb, 4096, 256, 256, 2048);
  gemm_smat_z<<<dim3(16, 16, 2), 256, 0, stream>>>(X12b, SmatB);
  smax_partA<<<dim3(32, 16, 2), 256, 0, stream>>>(SmatB, sm_pm, sm_pl, 2048);
  smax_partB<<<dim3(8, 2), 256, 0, stream>>>(sm_pm, sm_pl, sm_gm, sm_gi, 2048);
  smax_partC<<<dim3(32, 16, 2), 256, 0, stream>>>(SmatB, sm_gm, sm_gi, 2048);
  gemm_nn_res64_z<<<dim3(4, 32, 2), 256, 0, stream>>>(SmatB, X3sb, dt_b, XsKs);

  // ---- euclid -> aff_b ----
  row_norm_bf16<<<4096, 64, 0, stream>>>(XsKs, nxy, 256);
  gemm_bf16_nt<EPI_EUCLID><<<dim3(16, 16), 256, 0, stream>>>(
      XsKs, XsKs + (size_t)2048 * 256, nullptr, nullptr, aff_b, 2048, 2048, 256,
      nxy, nxy + 2048);

  // ---- skip3 (aff in-place) ----
  gemm_bf16_nt64<EPI_LEAKY_BN><<<dim3(4, 32), 256, 0, stream>>>(
      aff_b, s3w1, pb_sk3, nullptr, X12b, 2048, 256, 2048);
  gemm_smat_z<<<dim3(16, 16, 1), 256, 0, stream>>>(X12b, SmatB);
  gemm_bf16_nt<EPI_LEAKY_BN><<<dim3(16, 16), 256, 0, stream>>>(
      aff_b, s3w3, IN(25), nullptr, X3b_b, 2048, 2048, 2048, nullptr, nullptr);
  smax_partA<<<dim3(32, 16, 1), 256, 0, stream>>>(SmatB, sm_pm, sm_pl, 2048);
  smax_partB<<<dim3(8, 1), 256, 0, stream>>>(sm_pm, sm_pl, sm_gm, sm_gi, 2048);
  smax_partC<<<dim3(32, 16, 1), 256, 0, stream>>>(SmatB, sm_gm, sm_gi, 2048);
  gemm_bf16_nn_res<<<dim3(16, 16), 256, 0, stream>>>(SmatB, X3b_b, aff_b, aff_b, 2048, 2048, 2048);
  ushort_t* affs_b = aff_b;

  // ---- mask_scores -> top-S idx ----
  gemm_nt64_split<EPI_LEAKY, EPI_TANH><<<dim3(4, 32), 256, 0, stream>>>(
      affs_b, mw1, pb_msk, nullptr, X12b, 2048, 256, 2048, 128);
  gemm_tn_part<<<dim3(8, 8, 16), 256, 0, stream>>>(X12b, tnpt);
  gemm_tn_reduce<<<64, 256, 0, stream>>>(tnpt, Mm_b);
  gemm_bf16_nt64<EPI_LEAKY><<<dim3(32, 2), 256, 0, stream>>>(
      Mm_b, mw3, IN(31), A3, nullptr, 128, 2048, 128);
  mask_score<<<8, 256, 0, stream>>>(A3, IN(32), IN(33), svec);
  topk_rank<<<8, 256, 0, stream>>>(svec, idxb, 2048, S);

  // ---- B_bag + concat + fuse ----
  build_cat<<<2048, 256, 0, stream>>>(dt_b, affs_b, idxb, cat_b);
  gemm_bf16_nt64<EPI_LEAKY><<<dim3(4, 32), 256, 0, stream>>>(
      cat_b, fwp, IN(35), nullptr, Bfuse_b, 2048, 256, 512);

  // ---- attention 1 ----
  gemm_bf16_nt64<EPI_LEAKY><<<dim3(4, 32), 256, 0, stream>>>(
      Bfuse_b, a1fe, IN(37), nullptr, Hbuf_b, 2048, 256, 256);
  gemm_nt64_split<EPI_TANH, EPI_LEAKY><<<dim3(4, 32), 256, 0, stream>>>(
      Hbuf_b, a1v, pb_a1, AVU, nullptr, 2048, 256, 256, 128);
  attn_gate<<<512, 256, 0, stream>>>(AVU, IN(42), IN(43), avec, 2048);
  softmax_vec<<<1, 256, 0, stream>>>(avec, Awv, nullptr, 2048);
  colsum_part<<<16, 256, 0, stream>>>(Awv, Hbuf_b, part, 2048);
  colsum_fin<<<1, 256, 0, stream>>>(part, AH);
  gemv_act<<<1, 256, 0, stream>>>(AH, IN(44), IN(45), M1v, 256, 256, 1);
  build_cat2<<<2048, 512, 0, stream>>>(Bfuse_b, M1v, cat2_b);

  // ---- attention 2 (A -> output) ----
  gemm_bf16_nt64<EPI_LEAKY><<<dim3(4, 32), 256, 0, stream>>>(
      cat2_b, a2fe, IN(47), nullptr, Hbuf_b, 2048, 256, 512);
  gemm_nt64_split<EPI_TANH, EPI_LEAKY><<<dim3(4, 32), 256, 0, stream>>>(
      Hbuf_b, a2v, pb_a2, AVU, nullptr, 2048, 256, 256, 128);
  attn_gate<<<512, 256, 0, stream>>>(AVU, IN(52), IN(53), avec, 2048);
  softmax_vec<<<1, 256, 0, stream>>>(avec, Awv, out_f + 1, 2048);
  colsum_part<<<16, 256, 0, stream>>>(Awv, Hbuf_b, part, 2048);
  colsum_fin<<<1, 256, 0, stream>>>(part, AH2);

  // ---- final head -> Y ----
  final_head<<<1, 512, 0, stream>>>(AH2, IN(54), IN(55), IN(56), IN(57),
                                    IN(58), IN(59), out_f);
}